// Round 1
// 371.452 us; speedup vs baseline: 1.1327x; 1.1327x over previous
//
#include <hip/hip_runtime.h>

// CrossTableAttention on MI355X (gfx950)
// T=16 B=1024 D=1024 R=8 H=16 DH=64
//
// R5: port both GEMMs to the 256x256 8-phase schedule (T2+T3+T4+T5):
//     - 512 thr / 8 waves (2Mx4N), BK=64, acc[8][4], 128KiB LDS dbuf
//     - full 3-bit LDS XOR swizzle (chunk ^= row&7) via pre-swizzled
//       global source + linear global_load_lds dest (rule #21)
//     - per K-tile: 4 phases {ds_read quad | stage prefetch | barrier |
//       lgkmcnt(0) | setprio(1) 16xMFMA setprio(0) | barrier}, one
//       vmcnt(0) per tile boundary (tile-granular double buffer).
//     - gemm_qkv keeps fused [d][b] transpose epilogue (2 wm-passes in LDS).

typedef unsigned short u16;
typedef __attribute__((ext_vector_type(8))) short short8;   // 8 bf16 = 4 VGPRs
typedef __attribute__((ext_vector_type(4))) float f32x4;

__device__ __forceinline__ float bf2f(u16 u) {
  unsigned int x = ((unsigned int)u) << 16;
  return __uint_as_float(x);
}
__device__ __forceinline__ u16 f2bf(float f) {
  unsigned int x = __float_as_uint(f);
  unsigned int r = (x + 0x7fffu + ((x >> 16) & 1u)) >> 16;   // RNE
  return (u16)r;
}

// async global->LDS, 16B per lane; lds dest is wave-uniform base + lane*16
__device__ __forceinline__ void gld_lds16(const void* g, void* l) {
  __builtin_amdgcn_global_load_lds(
      (const __attribute__((address_space(1))) unsigned int*)(unsigned long long)g,
      (__attribute__((address_space(3))) unsigned int*)(unsigned int)(unsigned long long)l,
      16, 0, 0);
}

// ---------------------------------------------------------------- prep kernels

__global__ void relw_kernel(const float* __restrict__ rel_embs,
                            const float* __restrict__ w_rel,
                            const float* __restrict__ b_rel,
                            float* __restrict__ rel_w) {
  const int tr = blockIdx.x;            // t*8 + r, 128 total
  const float* row = rel_embs + (size_t)tr * 1024;
  const int lane = threadIdx.x;         // 64 threads
  float s = 0.f;
  for (int i = lane; i < 1024; i += 64) s += row[i] * w_rel[i];
  for (int off = 32; off > 0; off >>= 1) s += __shfl_down(s, off, 64);
  if (lane == 0) rel_w[tr] = 1.f / (1.f + __expf(-(s + b_rel[0])));
}

__global__ void cvt_f32_bf16(const float* __restrict__ in, u16* __restrict__ out, int n4) {
  int i = blockIdx.x * blockDim.x + threadIdx.x;
  if (i >= n4) return;
  float4 v = ((const float4*)in)[i];
  ushort4 o;
  o.x = f2bf(v.x); o.y = f2bf(v.y); o.z = f2bf(v.z); o.w = f2bf(v.w);
  ((ushort4*)out)[i] = o;
}

// all four 1024x1024 weight matrices in one launch: 4*262144 float4's
__global__ void cvt_w4(const float* __restrict__ Wq, const float* __restrict__ Wk,
                       const float* __restrict__ Wv, const float* __restrict__ Wo,
                       u16* __restrict__ Wcat, u16* __restrict__ Wob) {
  const int i = blockIdx.x * 256 + threadIdx.x;     // 0 .. 1048575
  const int w = i >> 18;                            // 262144 float4 per matrix
  const int j = i & 0x3ffff;
  const float* src = (w == 0) ? Wq : (w == 1) ? Wk : (w == 2) ? Wv : Wo;
  u16* dst = (w == 3) ? Wob : (Wcat + ((size_t)w << 20));
  float4 v = ((const float4*)src)[j];
  ushort4 o;
  o.x = f2bf(v.x); o.y = f2bf(v.y); o.z = f2bf(v.z); o.w = f2bf(v.w);
  ((ushort4*)dst)[j] = o;
}

// ---------------------------------------------------------------- 256^2 mainloop
// A [M,1024] row-major bf16, B [N,1024] row-major bf16 (out = x@W.T), K=1024.
// Block tile 256x256, BK=64, 512 threads = 8 waves (2M x 4N), wave 128x64 out.
// LDS 128KiB: buf0{A,B} buf1{A,B}, each region 256 rows x 64 bf16 (128B/row).
// Swizzle: 16B chunk c of row r lives at physical chunk c ^ (r&7) -> frag
// ds_read_b128 spreads 16 lanes over 8 chunk-columns = all 32 banks, 2-way.
// Staging: thread's slot s = r*512+tid -> phys (row=s>>3, pc=s&7); source is
// logical chunk pc ^ (row&7) so the linear global_load_lds dest is correct.

__device__ __forceinline__ void mainloop256(const u16* __restrict__ A,
                                            const u16* __restrict__ B,
                                            u16* lds, int m0, int n0,
                                            f32x4 (&acc)[8][4]) {
  const int tid  = threadIdx.x;          // 512
  const int lane = tid & 63;
  const int w    = tid >> 6;             // 8 waves
  const int wm   = w >> 2, wn = w & 3;
  const int fr   = lane & 15, fq = lane >> 4;
  const int swz  = fr & 7;

  const unsigned A0 = 0, B0 = 16384, A1 = 32768, B1 = 49152;  // u16 offsets

  // staging descriptors: row&7 and pc are r-invariant (r step = 64 rows)
  const int srow = tid >> 3;                       // row for slot r=0
  const int lc   = (tid & 7) ^ (srow & 7);         // logical chunk stored here
  const u16* a0p = A + (size_t)(m0 + srow) * 1024 + lc * 8;
  const u16* b0p = B + (size_t)(n0 + srow) * 1024 + lc * 8;
  const unsigned d0 = (unsigned)((tid & ~63) * 8); // wave-uniform dest (u16)

  // fragment read bases per (buffer, ksub); i/j become imm offsets (i*2048B)
  const u16 *ap0[2], *ap1[2], *bp0[2], *bp1[2];
#pragma unroll
  for (int ks = 0; ks < 2; ++ks) {
    const unsigned ck = (unsigned)((((ks << 2) + fq) ^ swz) << 3);
    ap0[ks] = lds + A0 + (wm * 128 + fr) * 64 + ck;
    ap1[ks] = lds + A1 + (wm * 128 + fr) * 64 + ck;
    bp0[ks] = lds + B0 + (wn * 64 + fr) * 64 + ck;
    bp1[ks] = lds + B1 + (wn * 64 + fr) * 64 + ck;
  }

#define STAGE4(g, AO, BO)                                                      \
  do {                                                                         \
    gld_lds16(a0p + (2*(g))   * 65536, lds + (AO) + d0 + (2*(g))   * 4096);    \
    gld_lds16(a0p + (2*(g)+1) * 65536, lds + (AO) + d0 + (2*(g)+1) * 4096);    \
    gld_lds16(b0p + (2*(g))   * 65536, lds + (BO) + d0 + (2*(g))   * 4096);    \
    gld_lds16(b0p + (2*(g)+1) * 65536, lds + (BO) + d0 + (2*(g)+1) * 4096);    \
  } while (0)

#define PHASE_Q(q, ap, STMT)                                                   \
  do {                                                                         \
    short8 a0k0 = *(const short8*)((ap)[0] + (2*(q))   * 1024);                \
    short8 a1k0 = *(const short8*)((ap)[0] + (2*(q)+1) * 1024);                \
    short8 a0k1 = *(const short8*)((ap)[1] + (2*(q))   * 1024);                \
    short8 a1k1 = *(const short8*)((ap)[1] + (2*(q)+1) * 1024);                \
    STMT;                                                                      \
    __builtin_amdgcn_s_barrier();                                              \
    asm volatile("s_waitcnt lgkmcnt(0)" ::: "memory");                         \
    __builtin_amdgcn_sched_barrier(0);                                         \
    __builtin_amdgcn_s_setprio(1);                                             \
    _Pragma("unroll")                                                          \
    for (int j = 0; j < 4; ++j) {                                              \
      acc[2*(q)][j]   = __builtin_amdgcn_mfma_f32_16x16x32_bf16(a0k0, bgv[j][0], acc[2*(q)][j],   0, 0, 0); \
      acc[2*(q)+1][j] = __builtin_amdgcn_mfma_f32_16x16x32_bf16(a1k0, bgv[j][0], acc[2*(q)+1][j], 0, 0, 0); \
    }                                                                          \
    _Pragma("unroll")                                                          \
    for (int j = 0; j < 4; ++j) {                                              \
      acc[2*(q)][j]   = __builtin_amdgcn_mfma_f32_16x16x32_bf16(a0k1, bgv[j][1], acc[2*(q)][j],   0, 0, 0); \
      acc[2*(q)+1][j] = __builtin_amdgcn_mfma_f32_16x16x32_bf16(a1k1, bgv[j][1], acc[2*(q)+1][j], 0, 0, 0); \
    }                                                                          \
    __builtin_amdgcn_s_setprio(0);                                             \
  } while (0)

// one K-tile (BK=64): 4 phases x 16 MFMA; prefetch next tile into (AO_N,BO_N)
#define KTILE(ap, bp, AO_N, BO_N, SG)                                          \
  do {                                                                         \
    short8 bgv[4][2];                                                          \
    _Pragma("unroll")                                                          \
    for (int j = 0; j < 4; ++j) {                                              \
      bgv[j][0] = *(const short8*)((bp)[0] + j * 1024);                        \
      bgv[j][1] = *(const short8*)((bp)[1] + j * 1024);                        \
    }                                                                          \
    PHASE_Q(0, ap, { if (SG) STAGE4(0, AO_N, BO_N); });                        \
    __builtin_amdgcn_s_barrier();                                              \
    PHASE_Q(1, ap, { if (SG) { STAGE4(1, AO_N, BO_N); a0p += 64; b0p += 64; } }); \
    __builtin_amdgcn_s_barrier();                                              \
    PHASE_Q(2, ap, {});                                                        \
    __builtin_amdgcn_s_barrier();                                              \
    PHASE_Q(3, ap, {});                                                        \
    if (SG) asm volatile("s_waitcnt vmcnt(0)" ::: "memory");                   \
    __builtin_amdgcn_s_barrier();                                              \
  } while (0)

  // prologue: stage tile 0 -> buf0, drain, sync
#pragma unroll
  for (int r = 0; r < 4; ++r) {
    gld_lds16(a0p + r * 65536, lds + A0 + d0 + r * 4096);
    gld_lds16(b0p + r * 65536, lds + B0 + d0 + r * 4096);
  }
  a0p += 64; b0p += 64;
  asm volatile("s_waitcnt vmcnt(0)" ::: "memory");
  __builtin_amdgcn_s_barrier();

  for (int it = 0; it < 8; ++it) {       // 16 K-tiles, 2 per iter (static parity)
    KTILE(ap0, bp0, A1, B1, true);
    KTILE(ap1, bp1, A0, B0, (it < 7));
  }
#undef STAGE4
#undef PHASE_Q
#undef KTILE
}

// GEMM1: X[16384,1024] @ Wcat[3072,1024].T -> Q/K/V stored TRANSPOSED [t][d][b]
__global__ __launch_bounds__(512, 2)
void gemm_qkv(const u16* __restrict__ A, const u16* __restrict__ Bw,
              const float* __restrict__ bq,
              u16* __restrict__ Qt, u16* __restrict__ Kt, u16* __restrict__ Vt) {
  __shared__ __align__(16) u16 lds[65536];   // 128 KiB
  const int n0 = blockIdx.x * 256;           // d within QKV-cat (256|1024 ok)
  const int m0 = blockIdx.y * 256;           // t*1024 + b (256|1024 ok)
  f32x4 acc[8][4];
#pragma unroll
  for (int i = 0; i < 8; ++i)
#pragma unroll
    for (int j = 0; j < 4; ++j) acc[i][j] = (f32x4){0.f, 0.f, 0.f, 0.f};

  mainloop256(A, Bw, lds, m0, n0, acc);
  // mainloop ends on a barrier; every wave's LDS reads are complete

  const int tid  = threadIdx.x;
  const int lane = tid & 63;
  const int w    = tid >> 6;
  const int wm   = w >> 2, wn = w & 3;
  const int colw = lane & 15, roww = (lane >> 4) * 4;
  const int t = m0 >> 10, b0 = m0 & 1023;
  const int sel = n0 >> 10, dbase = n0 & 1023;
  u16* outp = (sel == 0) ? Qt : (sel == 1) ? Kt : Vt;

  // two passes over the b-halves (wm): stage [256 d][128 b +pad8] in LDS,
  // then coalesced 16B-row writeout into [t][d][b].
  for (int pass = 0; pass < 2; ++pass) {
    if (wm == pass) {
#pragma unroll
      for (int j = 0; j < 4; ++j) {
        const int dl = wn * 64 + j * 16 + colw;
        const float badd = (sel == 0) ? bq[dbase + dl] : 0.f;
#pragma unroll
        for (int i = 0; i < 8; ++i) {
          const int bl = i * 16 + roww;
          const unsigned p0 = (unsigned)f2bf(acc[i][j][0] + badd)
                            | ((unsigned)f2bf(acc[i][j][1] + badd) << 16);
          const unsigned p1 = (unsigned)f2bf(acc[i][j][2] + badd)
                            | ((unsigned)f2bf(acc[i][j][3] + badd) << 16);
          *(unsigned*)(lds + dl * 136 + bl)     = p0;
          *(unsigned*)(lds + dl * 136 + bl + 2) = p1;
        }
      }
    }
    __syncthreads();
#pragma unroll
    for (int rr = 0; rr < 8; ++rr) {
      const int slot = rr * 512 + tid;          // 4096 slots = 256 rows x 16
      const int row = slot >> 4, c16 = slot & 15;
      const uint4 v = *(const uint4*)(lds + row * 136 + c16 * 8);
      *(uint4*)(outp + ((size_t)t << 20) + (size_t)(dbase + row) * 1024
                + b0 + pass * 128 + c16 * 8) = v;
    }
    __syncthreads();   // LDS reused by next pass
  }
}

// GEMM2: ctx[16384,1024] @ Wo[1024,1024].T + bo -> fp32 out
__global__ __launch_bounds__(512, 2)
void gemm_out(const u16* __restrict__ A, const u16* __restrict__ Bw,
              const float* __restrict__ bo, float* __restrict__ out) {
  __shared__ __align__(16) u16 lds[65536];
  const int n0 = blockIdx.x * 256;
  const int m0 = blockIdx.y * 256;
  f32x4 acc[8][4];
#pragma unroll
  for (int i = 0; i < 8; ++i)
#pragma unroll
    for (int j = 0; j < 4; ++j) acc[i][j] = (f32x4){0.f, 0.f, 0.f, 0.f};

  mainloop256(A, Bw, lds, m0, n0, acc);

  const int lane = threadIdx.x & 63;
  const int w    = threadIdx.x >> 6;
  const int wm   = w >> 2, wn = w & 3;
  const int colw = lane & 15, roww = (lane >> 4) * 4;
#pragma unroll
  for (int j = 0; j < 4; ++j) {
    const int gn = n0 + wn * 64 + j * 16 + colw;
    const float bov = bo[gn];
#pragma unroll
    for (int i = 0; i < 8; ++i) {
      const int gm = m0 + wm * 128 + i * 16 + roww;
#pragma unroll
      for (int r = 0; r < 4; ++r)
        out[(size_t)(gm + r) * 1024 + gn] = acc[i][j][r] + bov;
    }
  }
}

// ---------------------------------------------------------------- attention
// attn5: ONE b per thread (262144 threads = 4096 waves = 16 waves/CU).
// Streams d; loads are 2B/lane (128B/wave contiguous). acc[8] in regs.
// Output staged per 32-d half via LDS (pad 34 -> 2-way banks), coalesced rows.
__global__ __launch_bounds__(256)
void attn5(const u16* __restrict__ Qt, const u16* __restrict__ Kt,
           const u16* __restrict__ Vt,
           const float* __restrict__ relw, const int* __restrict__ rel_idx,
           const float* __restrict__ bk, const float* __restrict__ bv,
           u16* __restrict__ ctx) {
  const int tid = threadIdx.x;
  const int h = blockIdx.y, t = blockIdx.z;
  const int b0 = blockIdx.x * 256;          // block covers b0 .. b0+255
  const int b = b0 + tid;
  const int hd = h * 64;

  __shared__ u16  st[256 * 34];             // [256 b][32 d + 2 pad]  17.0KB
  __shared__ float bks[64], bvs[64], rws[8];
  __shared__ int   rids[8];

  if (tid < 64) { bks[tid] = bk[hd + tid]; bvs[tid] = bv[hd + tid]; }
  else if (tid < 72) { rws[tid - 64] = relw[t * 8 + (tid - 64)];
                       rids[tid - 64] = rel_idx[t * 8 + (tid - 64)]; }
  __syncthreads();

  // element offsets at d=0 into [t][1024 d][1024 b] arrays
  const unsigned qoff = ((unsigned)t << 20) + ((unsigned)hd << 10) + (unsigned)b;
  unsigned koff[8];
#pragma unroll
  for (int r = 0; r < 8; ++r)
    koff[r] = ((unsigned)rids[r] << 20) + ((unsigned)hd << 10) + (unsigned)b;

  // ---- scores
  float acc[8];
#pragma unroll
  for (int r = 0; r < 8; ++r) acc[r] = 0.f;
  float qbk = 0.f;
#pragma unroll 4
  for (int d = 0; d < 64; ++d) {
    const float q = bf2f(Qt[qoff + d * 1024]);
    qbk += q * bks[d];
#pragma unroll
    for (int r = 0; r < 8; ++r)
      acc[r] += q * bf2f(Kt[koff[r] + d * 1024]);
  }

  // ---- softmax -> w[r] = attn_r * rw_r
  float w[8];
  {
    float s[8], mx = -1e30f;
#pragma unroll
    for (int r = 0; r < 8; ++r) {
      s[r] = (rws[r] * acc[r] + qbk) * 0.125f;
      mx = fmaxf(mx, s[r]);
    }
    float sum = 0.f;
#pragma unroll
    for (int r = 0; r < 8; ++r) { s[r] = __expf(s[r] - mx); sum += s[r]; }
    const float inv = 1.f / sum;
#pragma unroll
    for (int r = 0; r < 8; ++r) w[r] = s[r] * inv * rws[r];
  }

  // ---- context: two 32-d halves; stage [b][d] in LDS, coalesced writeout
  for (int half = 0; half < 2; ++half) {
#pragma unroll
    for (int dp = 0; dp < 32; dp += 2) {
      const int d = half * 32 + dp;
      float o0 = bvs[d];
      float o1 = bvs[d + 1];
#pragma unroll
      for (int r = 0; r < 8; ++r) {
        o0 += w[r] * bf2f(Vt[koff[r] + d * 1024]);
        o1 += w[r] * bf2f(Vt[koff[r] + (d + 1) * 1024]);
      }
      const unsigned p = (unsigned)f2bf(o0) | ((unsigned)f2bf(o1) << 16);
      *(unsigned*)(st + tid * 34 + dp) = p;   // byte 68*tid+2dp, 4B-aligned
    }
    __syncthreads();
    // writeout: 256 rows x 64B (32 d); 8 lanes x 8B per row, 8 passes
    {
      const int sub = tid & 7;
      const int rbase = tid >> 3;              // 0..31
#pragma unroll
      for (int p = 0; p < 8; ++p) {
        const int row = p * 32 + rbase;
        const uint2 v = *(const uint2*)(st + row * 34 + sub * 4);
        *(uint2*)(ctx + ((size_t)(t * 1024 + b0 + row)) * 1024
                  + hd + half * 32 + sub * 4) = v;
      }
    }
    __syncthreads();   // st reused by next half
  }
}

// ---------------------------------------------------------------- launch

extern "C" void kernel_launch(void* const* d_in, const int* in_sizes, int n_in,
                              void* d_out, int out_size, void* d_ws, size_t ws_size,
                              hipStream_t stream) {
  const float* table = (const float*)d_in[0];
  const float* rele  = (const float*)d_in[1];
  const int*   ridx  = (const int*)d_in[2];
  const float* Wq    = (const float*)d_in[3];
  const float* bq    = (const float*)d_in[4];
  const float* Wk    = (const float*)d_in[5];
  const float* bk    = (const float*)d_in[6];
  const float* Wv    = (const float*)d_in[7];
  const float* bv    = (const float*)d_in[8];
  const float* Wo    = (const float*)d_in[9];
  const float* bo    = (const float*)d_in[10];
  const float* wr    = (const float*)d_in[11];
  const float* br    = (const float*)d_in[12];
  float* out = (float*)d_out;

  char* ws = (char*)d_ws;
  const size_t MB = 1024 * 1024;
  u16*  Xbf  = (u16*)(ws);                    // 32 MB  [16384,1024] bf16 (also ctx)
  u16*  Kt   = (u16*)(ws + 32  * MB);         // 32 MB  [16][1024 d][1024 b]
  u16*  Vt   = (u16*)(ws + 64  * MB);         // 32 MB
  u16*  Qt   = (u16*)(ws + 96  * MB);         // 32 MB
  u16*  Wcat = (u16*)(ws + 128 * MB);         // 6 MB   [3072,1024] (Wq|Wk|Wv)
  u16*  Wob  = (u16*)(ws + 134 * MB);         // 2 MB
  float* relw = (float*)(ws + 136 * MB);      // 512 B
  u16*  ctxb = Xbf;                           // reuse: Xbf dead after gemm_qkv

  relw_kernel<<<128, 64, 0, stream>>>(rele, wr, br, relw);
  cvt_f32_bf16<<<16384, 256, 0, stream>>>(table, Xbf, 4194304);
  cvt_w4<<<4096, 256, 0, stream>>>(Wq, Wk, Wv, Wo, Wcat, Wob);

  gemm_qkv<<<dim3(12, 64), 512, 0, stream>>>(Xbf, Wcat, bq, Qt, Kt, Vt);
  attn5<<<dim3(4, 16, 16), 256, 0, stream>>>(Qt, Kt, Vt, relw, ridx, bk, bv, ctxb);
  gemm_out<<<dim3(4, 64), 512, 0, stream>>>(ctxb, Wob, bo, out);
}

// Round 2
// 365.826 us; speedup vs baseline: 1.1501x; 1.0154x over previous
//
#include <hip/hip_runtime.h>

// CrossTableAttention on MI355X (gfx950)
// T=16 B=1024 D=1024 R=8 H=16 DH=64
//
// R6: (1) counted-vmcnt pipeline (T4) in mainloop256: stage issues spread
//         phase0=B(t+1), phase1=A_r0,r2(t+1), phase2=A_r1,r3(t+1);
//         waits only vmcnt(6) @ 1->2 boundary and vmcnt(2) @ tile boundary
//         (never 0 in steady state; last tile peeled with drain counts).
//         Ledger: phases {0,1} read A loads {r0,r2}, {2,3} read {r1,r3},
//         B needed whole at tile start (bgv).
//     (2) T1 bijective XCD swizzle on both GEMM grids (768, 256 both %8==0).

typedef unsigned short u16;
typedef __attribute__((ext_vector_type(8))) short short8;   // 8 bf16 = 4 VGPRs
typedef __attribute__((ext_vector_type(4))) float f32x4;

__device__ __forceinline__ float bf2f(u16 u) {
  unsigned int x = ((unsigned int)u) << 16;
  return __uint_as_float(x);
}
__device__ __forceinline__ u16 f2bf(float f) {
  unsigned int x = __float_as_uint(f);
  unsigned int r = (x + 0x7fffu + ((x >> 16) & 1u)) >> 16;   // RNE
  return (u16)r;
}

// async global->LDS, 16B per lane; lds dest is wave-uniform base + lane*16
__device__ __forceinline__ void gld_lds16(const void* g, void* l) {
  __builtin_amdgcn_global_load_lds(
      (const __attribute__((address_space(1))) unsigned int*)(unsigned long long)g,
      (__attribute__((address_space(3))) unsigned int*)(unsigned int)(unsigned long long)l,
      16, 0, 0);
}

#define VWAIT(N) asm volatile("s_waitcnt vmcnt(" #N ")" ::: "memory")

// ---------------------------------------------------------------- prep kernels

__global__ void relw_kernel(const float* __restrict__ rel_embs,
                            const float* __restrict__ w_rel,
                            const float* __restrict__ b_rel,
                            float* __restrict__ rel_w) {
  const int tr = blockIdx.x;            // t*8 + r, 128 total
  const float* row = rel_embs + (size_t)tr * 1024;
  const int lane = threadIdx.x;         // 64 threads
  float s = 0.f;
  for (int i = lane; i < 1024; i += 64) s += row[i] * w_rel[i];
  for (int off = 32; off > 0; off >>= 1) s += __shfl_down(s, off, 64);
  if (lane == 0) rel_w[tr] = 1.f / (1.f + __expf(-(s + b_rel[0])));
}

__global__ void cvt_f32_bf16(const float* __restrict__ in, u16* __restrict__ out, int n4) {
  int i = blockIdx.x * blockDim.x + threadIdx.x;
  if (i >= n4) return;
  float4 v = ((const float4*)in)[i];
  ushort4 o;
  o.x = f2bf(v.x); o.y = f2bf(v.y); o.z = f2bf(v.z); o.w = f2bf(v.w);
  ((ushort4*)out)[i] = o;
}

// all four 1024x1024 weight matrices in one launch: 4*262144 float4's
__global__ void cvt_w4(const float* __restrict__ Wq, const float* __restrict__ Wk,
                       const float* __restrict__ Wv, const float* __restrict__ Wo,
                       u16* __restrict__ Wcat, u16* __restrict__ Wob) {
  const int i = blockIdx.x * 256 + threadIdx.x;     // 0 .. 1048575
  const int w = i >> 18;                            // 262144 float4 per matrix
  const int j = i & 0x3ffff;
  const float* src = (w == 0) ? Wq : (w == 1) ? Wk : (w == 2) ? Wv : Wo;
  u16* dst = (w == 3) ? Wob : (Wcat + ((size_t)w << 20));
  float4 v = ((const float4*)src)[j];
  ushort4 o;
  o.x = f2bf(v.x); o.y = f2bf(v.y); o.z = f2bf(v.z); o.w = f2bf(v.w);
  ((ushort4*)dst)[j] = o;
}

// ---------------------------------------------------------------- 256^2 mainloop
// A [M,1024] row-major bf16, B [N,1024] row-major bf16 (out = x@W.T), K=1024.
// Block tile 256x256, BK=64, 512 threads = 8 waves (2M x 4N), wave 128x64 out.
// LDS 128KiB: buf0{A,B} buf1{A,B}, each region 256 rows x 64 bf16 (128B/row).
// Swizzle: 16B chunk c of row r lives at physical chunk c ^ (r&7).
// Pipeline: per tile t issue next-tile stages ph0:B0-3 ph1:A_r0,r2 ph2:A_r1,r3;
// counted waits vmcnt(6) @ ph1->2 (A_r1,r3 of t land), vmcnt(2) @ tile end
// (B+A_r0,r2 of t+1 land; A_r1,r3 of t+1 stay in flight).

__device__ __forceinline__ void mainloop256(const u16* __restrict__ A,
                                            const u16* __restrict__ B,
                                            u16* lds, int m0, int n0,
                                            f32x4 (&acc)[8][4]) {
  const int tid  = threadIdx.x;          // 512
  const int lane = tid & 63;
  const int w    = tid >> 6;             // 8 waves
  const int wm   = w >> 2, wn = w & 3;
  const int fr   = lane & 15, fq = lane >> 4;
  const int swz  = fr & 7;

  const unsigned A0 = 0, B0 = 16384, A1 = 32768, B1 = 49152;  // u16 offsets

  // staging descriptors: row&7 and pc are r-invariant (r step = 64 rows)
  const int srow = tid >> 3;                       // row for slot r=0
  const int lc   = (tid & 7) ^ (srow & 7);         // logical chunk stored here
  const u16* a0p = A + (size_t)(m0 + srow) * 1024 + lc * 8;
  const u16* b0p = B + (size_t)(n0 + srow) * 1024 + lc * 8;
  const unsigned d0 = (unsigned)((tid & ~63) * 8); // wave-uniform dest (u16)

  // fragment read bases per (buffer, ksub); i becomes imm offset (i*2048B)
  const u16 *ap0[2], *ap1[2], *bp0[2], *bp1[2];
#pragma unroll
  for (int ks = 0; ks < 2; ++ks) {
    const unsigned ck = (unsigned)((((ks << 2) + fq) ^ swz) << 3);
    ap0[ks] = lds + A0 + (wm * 128 + fr) * 64 + ck;
    ap1[ks] = lds + A1 + (wm * 128 + fr) * 64 + ck;
    bp0[ks] = lds + B0 + (wn * 64 + fr) * 64 + ck;
    bp1[ks] = lds + B1 + (wn * 64 + fr) * 64 + ck;
  }

#define STAGE_B4(BO)                                                           \
  do {                                                                         \
    gld_lds16(b0p + 0 * 65536, lds + (BO) + d0 + 0 * 4096);                    \
    gld_lds16(b0p + 1 * 65536, lds + (BO) + d0 + 1 * 4096);                    \
    gld_lds16(b0p + 2 * 65536, lds + (BO) + d0 + 2 * 4096);                    \
    gld_lds16(b0p + 3 * 65536, lds + (BO) + d0 + 3 * 4096);                    \
    b0p += 64;                                                                 \
  } while (0)

#define STAGE_A2(ra, rb, AO)                                                   \
  do {                                                                         \
    gld_lds16(a0p + (ra) * 65536, lds + (AO) + d0 + (ra) * 4096);              \
    gld_lds16(a0p + (rb) * 65536, lds + (AO) + d0 + (rb) * 4096);              \
  } while (0)

#define PHASE_Q(q, ap, STMT)                                                   \
  do {                                                                         \
    short8 a0k0 = *(const short8*)((ap)[0] + (2*(q))   * 1024);                \
    short8 a1k0 = *(const short8*)((ap)[0] + (2*(q)+1) * 1024);                \
    short8 a0k1 = *(const short8*)((ap)[1] + (2*(q))   * 1024);                \
    short8 a1k1 = *(const short8*)((ap)[1] + (2*(q)+1) * 1024);                \
    STMT;                                                                      \
    __builtin_amdgcn_s_barrier();                                              \
    asm volatile("s_waitcnt lgkmcnt(0)" ::: "memory");                         \
    __builtin_amdgcn_sched_barrier(0);                                         \
    __builtin_amdgcn_s_setprio(1);                                             \
    _Pragma("unroll")                                                          \
    for (int j = 0; j < 4; ++j) {                                              \
      acc[2*(q)][j]   = __builtin_amdgcn_mfma_f32_16x16x32_bf16(a0k0, bgv[j][0], acc[2*(q)][j],   0, 0, 0); \
      acc[2*(q)+1][j] = __builtin_amdgcn_mfma_f32_16x16x32_bf16(a1k0, bgv[j][0], acc[2*(q)+1][j], 0, 0, 0); \
    }                                                                          \
    _Pragma("unroll")                                                          \
    for (int j = 0; j < 4; ++j) {                                              \
      acc[2*(q)][j]   = __builtin_amdgcn_mfma_f32_16x16x32_bf16(a0k1, bgv[j][1], acc[2*(q)][j],   0, 0, 0); \
      acc[2*(q)+1][j] = __builtin_amdgcn_mfma_f32_16x16x32_bf16(a1k1, bgv[j][1], acc[2*(q)+1][j], 0, 0, 0); \
    }                                                                          \
    __builtin_amdgcn_s_setprio(0);                                             \
  } while (0)

#define BGV_LOAD(bp)                                                           \
  _Pragma("unroll")                                                            \
  for (int j = 0; j < 4; ++j) {                                                \
    bgv[j][0] = *(const short8*)((bp)[0] + j * 1024);                          \
    bgv[j][1] = *(const short8*)((bp)[1] + j * 1024);                          \
  }

// steady-state K-tile: stages next tile into (AO_N,BO_N); counted waits only
#define KTILE(ap, bp, AO_N, BO_N)                                              \
  do {                                                                         \
    short8 bgv[4][2];                                                          \
    BGV_LOAD(bp);                                                              \
    PHASE_Q(0, ap, { STAGE_B4(BO_N); });                                       \
    __builtin_amdgcn_s_barrier();                                              \
    PHASE_Q(1, ap, { STAGE_A2(0, 2, AO_N); });                                 \
    VWAIT(6);                                                                  \
    __builtin_amdgcn_s_barrier();                                              \
    PHASE_Q(2, ap, { STAGE_A2(1, 3, AO_N); a0p += 64; });                      \
    __builtin_amdgcn_s_barrier();                                              \
    PHASE_Q(3, ap, {});                                                       \
    VWAIT(2);                                                                  \
    __builtin_amdgcn_s_barrier();                                              \
  } while (0)

// last K-tile: no staging; drain the 2 leftover A loads at ph1->2
#define KTILE_LAST(ap, bp)                                                     \
  do {                                                                         \
    short8 bgv[4][2];                                                          \
    BGV_LOAD(bp);                                                              \
    PHASE_Q(0, ap, {});                                                       \
    __builtin_amdgcn_s_barrier();                                              \
    PHASE_Q(1, ap, {});                                                       \
    VWAIT(0);                                                                  \
    __builtin_amdgcn_s_barrier();                                              \
    PHASE_Q(2, ap, {});                                                       \
    __builtin_amdgcn_s_barrier();                                              \
    PHASE_Q(3, ap, {});                                                       \
    __builtin_amdgcn_s_barrier();                                              \
  } while (0)

  // prologue: stage tile 0 -> buf0 in pipeline order B0-3, A_r0, A_r2, A_r1, A_r3
  gld_lds16(b0p + 0 * 65536, lds + B0 + d0 + 0 * 4096);
  gld_lds16(b0p + 1 * 65536, lds + B0 + d0 + 1 * 4096);
  gld_lds16(b0p + 2 * 65536, lds + B0 + d0 + 2 * 4096);
  gld_lds16(b0p + 3 * 65536, lds + B0 + d0 + 3 * 4096);
  gld_lds16(a0p + 0 * 65536, lds + A0 + d0 + 0 * 4096);
  gld_lds16(a0p + 2 * 65536, lds + A0 + d0 + 2 * 4096);
  gld_lds16(a0p + 1 * 65536, lds + A0 + d0 + 1 * 4096);
  gld_lds16(a0p + 3 * 65536, lds + A0 + d0 + 3 * 4096);
  a0p += 64; b0p += 64;
  VWAIT(2);                       // B(0)+A_r0,r2 landed; A_r1,r3 in flight
  __builtin_amdgcn_s_barrier();

  for (int it = 0; it < 7; ++it) {       // tiles 0..13
    KTILE(ap0, bp0, A1, B1);
    KTILE(ap1, bp1, A0, B0);
  }
  KTILE(ap0, bp0, A1, B1);               // tile 14 (stages tile 15)
  KTILE_LAST(ap1, bp1);                  // tile 15

#undef STAGE_B4
#undef STAGE_A2
#undef PHASE_Q
#undef BGV_LOAD
#undef KTILE
#undef KTILE_LAST
}

// bijective XCD swizzle for nwg % 8 == 0
__device__ __forceinline__ void xcd_swizzle(int nx, int ny, int& bx, int& by) {
  const int nwg = nx * ny;
  int bid = by * nx + bx;
  bid = (bid & 7) * (nwg >> 3) + (bid >> 3);
  bx = bid % nx;
  by = bid / nx;
}

// GEMM1: X[16384,1024] @ Wcat[3072,1024].T -> Q/K/V stored TRANSPOSED [t][d][b]
__global__ __launch_bounds__(512, 2)
void gemm_qkv(const u16* __restrict__ A, const u16* __restrict__ Bw,
              const float* __restrict__ bq,
              u16* __restrict__ Qt, u16* __restrict__ Kt, u16* __restrict__ Vt) {
  __shared__ __align__(16) u16 lds[65536];   // 128 KiB
  int bx = blockIdx.x, by = blockIdx.y;
  xcd_swizzle(gridDim.x, gridDim.y, bx, by);
  const int n0 = bx * 256;                   // d within QKV-cat (256|1024 ok)
  const int m0 = by * 256;                   // t*1024 + b (256|1024 ok)
  f32x4 acc[8][4];
#pragma unroll
  for (int i = 0; i < 8; ++i)
#pragma unroll
    for (int j = 0; j < 4; ++j) acc[i][j] = (f32x4){0.f, 0.f, 0.f, 0.f};

  mainloop256(A, Bw, lds, m0, n0, acc);
  // mainloop ends on a barrier; every wave's LDS reads are complete

  const int tid  = threadIdx.x;
  const int lane = tid & 63;
  const int w    = tid >> 6;
  const int wm   = w >> 2, wn = w & 3;
  const int colw = lane & 15, roww = (lane >> 4) * 4;
  const int t = m0 >> 10, b0 = m0 & 1023;
  const int sel = n0 >> 10, dbase = n0 & 1023;
  u16* outp = (sel == 0) ? Qt : (sel == 1) ? Kt : Vt;

  // two passes over the b-halves (wm): stage [256 d][128 b +pad8] in LDS,
  // then coalesced 16B-row writeout into [t][d][b].
  for (int pass = 0; pass < 2; ++pass) {
    if (wm == pass) {
#pragma unroll
      for (int j = 0; j < 4; ++j) {
        const int dl = wn * 64 + j * 16 + colw;
        const float badd = (sel == 0) ? bq[dbase + dl] : 0.f;
#pragma unroll
        for (int i = 0; i < 8; ++i) {
          const int bl = i * 16 + roww;
          const unsigned p0 = (unsigned)f2bf(acc[i][j][0] + badd)
                            | ((unsigned)f2bf(acc[i][j][1] + badd) << 16);
          const unsigned p1 = (unsigned)f2bf(acc[i][j][2] + badd)
                            | ((unsigned)f2bf(acc[i][j][3] + badd) << 16);
          *(unsigned*)(lds + dl * 136 + bl)     = p0;
          *(unsigned*)(lds + dl * 136 + bl + 2) = p1;
        }
      }
    }
    __syncthreads();
#pragma unroll
    for (int rr = 0; rr < 8; ++rr) {
      const int slot = rr * 512 + tid;          // 4096 slots = 256 rows x 16
      const int row = slot >> 4, c16 = slot & 15;
      const uint4 v = *(const uint4*)(lds + row * 136 + c16 * 8);
      *(uint4*)(outp + ((size_t)t << 20) + (size_t)(dbase + row) * 1024
                + b0 + pass * 128 + c16 * 8) = v;
    }
    __syncthreads();   // LDS reused by next pass
  }
}

// GEMM2: ctx[16384,1024] @ Wo[1024,1024].T + bo -> fp32 out
__global__ __launch_bounds__(512, 2)
void gemm_out(const u16* __restrict__ A, const u16* __restrict__ Bw,
              const float* __restrict__ bo, float* __restrict__ out) {
  __shared__ __align__(16) u16 lds[65536];
  int bx = blockIdx.x, by = blockIdx.y;
  xcd_swizzle(gridDim.x, gridDim.y, bx, by);
  const int n0 = bx * 256;
  const int m0 = by * 256;
  f32x4 acc[8][4];
#pragma unroll
  for (int i = 0; i < 8; ++i)
#pragma unroll
    for (int j = 0; j < 4; ++j) acc[i][j] = (f32x4){0.f, 0.f, 0.f, 0.f};

  mainloop256(A, Bw, lds, m0, n0, acc);

  const int lane = threadIdx.x & 63;
  const int w    = threadIdx.x >> 6;
  const int wm   = w >> 2, wn = w & 3;
  const int colw = lane & 15, roww = (lane >> 4) * 4;
#pragma unroll
  for (int j = 0; j < 4; ++j) {
    const int gn = n0 + wn * 64 + j * 16 + colw;
    const float bov = bo[gn];
#pragma unroll
    for (int i = 0; i < 8; ++i) {
      const int gm = m0 + wm * 128 + i * 16 + roww;
#pragma unroll
      for (int r = 0; r < 4; ++r)
        out[(size_t)(gm + r) * 1024 + gn] = acc[i][j][r] + bov;
    }
  }
}

// ---------------------------------------------------------------- attention
// attn5: ONE b per thread (262144 threads = 4096 waves = 16 waves/CU).
// Streams d; loads are 2B/lane (128B/wave contiguous). acc[8] in regs.
// Output staged per 32-d half via LDS (pad 34 -> 2-way banks), coalesced rows.
__global__ __launch_bounds__(256)
void attn5(const u16* __restrict__ Qt, const u16* __restrict__ Kt,
           const u16* __restrict__ Vt,
           const float* __restrict__ relw, const int* __restrict__ rel_idx,
           const float* __restrict__ bk, const float* __restrict__ bv,
           u16* __restrict__ ctx) {
  const int tid = threadIdx.x;
  const int h = blockIdx.y, t = blockIdx.z;
  const int b0 = blockIdx.x * 256;          // block covers b0 .. b0+255
  const int b = b0 + tid;
  const int hd = h * 64;

  __shared__ u16  st[256 * 34];             // [256 b][32 d + 2 pad]  17.0KB
  __shared__ float bks[64], bvs[64], rws[8];
  __shared__ int   rids[8];

  if (tid < 64) { bks[tid] = bk[hd + tid]; bvs[tid] = bv[hd + tid]; }
  else if (tid < 72) { rws[tid - 64] = relw[t * 8 + (tid - 64)];
                       rids[tid - 64] = rel_idx[t * 8 + (tid - 64)]; }
  __syncthreads();

  // element offsets at d=0 into [t][1024 d][1024 b] arrays
  const unsigned qoff = ((unsigned)t << 20) + ((unsigned)hd << 10) + (unsigned)b;
  unsigned koff[8];
#pragma unroll
  for (int r = 0; r < 8; ++r)
    koff[r] = ((unsigned)rids[r] << 20) + ((unsigned)hd << 10) + (unsigned)b;

  // ---- scores
  float acc[8];
#pragma unroll
  for (int r = 0; r < 8; ++r) acc[r] = 0.f;
  float qbk = 0.f;
#pragma unroll 4
  for (int d = 0; d < 64; ++d) {
    const float q = bf2f(Qt[qoff + d * 1024]);
    qbk += q * bks[d];
#pragma unroll
    for (int r = 0; r < 8; ++r)
      acc[r] += q * bf2f(Kt[koff[r] + d * 1024]);
  }

  // ---- softmax -> w[r] = attn_r * rw_r
  float w[8];
  {
    float s[8], mx = -1e30f;
#pragma unroll
    for (int r = 0; r < 8; ++r) {
      s[r] = (rws[r] * acc[r] + qbk) * 0.125f;
      mx = fmaxf(mx, s[r]);
    }
    float sum = 0.f;
#pragma unroll
    for (int r = 0; r < 8; ++r) { s[r] = __expf(s[r] - mx); sum += s[r]; }
    const float inv = 1.f / sum;
#pragma unroll
    for (int r = 0; r < 8; ++r) w[r] = s[r] * inv * rws[r];
  }

  // ---- context: two 32-d halves; stage [b][d] in LDS, coalesced writeout
  for (int half = 0; half < 2; ++half) {
#pragma unroll
    for (int dp = 0; dp < 32; dp += 2) {
      const int d = half * 32 + dp;
      float o0 = bvs[d];
      float o1 = bvs[d + 1];
#pragma unroll
      for (int r = 0; r < 8; ++r) {
        o0 += w[r] * bf2f(Vt[koff[r] + d * 1024]);
        o1 += w[r] * bf2f(Vt[koff[r] + (d + 1) * 1024]);
      }
      const unsigned p = (unsigned)f2bf(o0) | ((unsigned)f2bf(o1) << 16);
      *(unsigned*)(st + tid * 34 + dp) = p;   // byte 68*tid+2dp, 4B-aligned
    }
    __syncthreads();
    // writeout: 256 rows x 64B (32 d); 8 lanes x 8B per row, 8 passes
    {
      const int sub = tid & 7;
      const int rbase = tid >> 3;              // 0..31
#pragma unroll
      for (int p = 0; p < 8; ++p) {
        const int row = p * 32 + rbase;
        const uint2 v = *(const uint2*)(st + row * 34 + sub * 4);
        *(uint2*)(ctx + ((size_t)(t * 1024 + b0 + row)) * 1024
                  + hd + half * 32 + sub * 4) = v;
      }
    }
    __syncthreads();   // st reused by next half
  }
}

// ---------------------------------------------------------------- launch

extern "C" void kernel_launch(void* const* d_in, const int* in_sizes, int n_in,
                              void* d_out, int out_size, void* d_ws, size_t ws_size,
                              hipStream_t stream) {
  const float* table = (const float*)d_in[0];
  const float* rele  = (const float*)d_in[1];
  const int*   ridx  = (const int*)d_in[2];
  const float* Wq    = (const float*)d_in[3];
  const float* bq    = (const float*)d_in[4];
  const float* Wk    = (const float*)d_in[5];
  const float* bk    = (const float*)d_in[6];
  const float* Wv    = (const float*)d_in[7];
  const float* bv    = (const float*)d_in[8];
  const float* Wo    = (const float*)d_in[9];
  const float* bo    = (const float*)d_in[10];
  const float* wr    = (const float*)d_in[11];
  const float* br    = (const float*)d_in[12];
  float* out = (float*)d_out;

  char* ws = (char*)d_ws;
  const size_t MB = 1024 * 1024;
  u16*  Xbf  = (u16*)(ws);                    // 32 MB  [16384,1024] bf16 (also ctx)
  u16*  Kt   = (u16*)(ws + 32  * MB);         // 32 MB  [16][1024 d][1024 b]
  u16*  Vt   = (u16*)(ws + 64  * MB);         // 32 MB
  u16*  Qt   = (u16*)(ws + 96  * MB);         // 32 MB
  u16*  Wcat = (u16*)(ws + 128 * MB);         // 6 MB   [3072,1024] (Wq|Wk|Wv)
  u16*  Wob  = (u16*)(ws + 134 * MB);         // 2 MB
  float* relw = (float*)(ws + 136 * MB);      // 512 B
  u16*  ctxb = Xbf;                           // reuse: Xbf dead after gemm_qkv

  relw_kernel<<<128, 64, 0, stream>>>(rele, wr, br, relw);
  cvt_f32_bf16<<<16384, 256, 0, stream>>>(table, Xbf, 4194304);
  cvt_w4<<<4096, 256, 0, stream>>>(Wq, Wk, Wv, Wo, Wcat, Wob);

  gemm_qkv<<<dim3(12, 64), 512, 0, stream>>>(Xbf, Wcat, bq, Qt, Kt, Vt);
  attn5<<<dim3(4, 16, 16), 256, 0, stream>>>(Qt, Kt, Vt, relw, ridx, bk, bv, ctxb);
  gemm_out<<<dim3(4, 64), 512, 0, stream>>>(ctxb, Wob, bo, out);
}

// Round 3
// 359.754 us; speedup vs baseline: 1.1695x; 1.0169x over previous
//
#include <hip/hip_runtime.h>

// CrossTableAttention on MI355X (gfx950)
// T=16 B=1024 D=1024 R=8 H=16 DH=64
//
// R7: (1) drop explicit lgkmcnt(0)+sched_barrier(0) before MFMA clusters:
//         let the compiler emit counted lgkmcnt so MFMAs start as soon as
//         their operands land (overlap LDS drain with MFMA; m97 evidence).
//         Correctness: in-order issue => a wave at a barrier has retired its
//         reads; cross-tile hoists blocked by VWAIT "memory" clobbers;
//         __syncthreads() (real fence) before LDS-reusing epilogue.
//     (2) __launch_bounds__(512,1): LDS-bound at 1 block/CU, free the RA.
//     (3) gemm_qkv epilogue: both wm-halves scatter concurrently into two
//         64KiB regions, XOR-swizzled (byte ^= (d&7)<<4), paired 8B stores,
//         single __syncthreads (no idle half-block).

typedef unsigned short u16;
typedef __attribute__((ext_vector_type(8))) short short8;   // 8 bf16 = 4 VGPRs
typedef __attribute__((ext_vector_type(4))) float f32x4;

__device__ __forceinline__ float bf2f(u16 u) {
  unsigned int x = ((unsigned int)u) << 16;
  return __uint_as_float(x);
}
__device__ __forceinline__ u16 f2bf(float f) {
  unsigned int x = __float_as_uint(f);
  unsigned int r = (x + 0x7fffu + ((x >> 16) & 1u)) >> 16;   // RNE
  return (u16)r;
}

// async global->LDS, 16B per lane; lds dest is wave-uniform base + lane*16
__device__ __forceinline__ void gld_lds16(const void* g, void* l) {
  __builtin_amdgcn_global_load_lds(
      (const __attribute__((address_space(1))) unsigned int*)(unsigned long long)g,
      (__attribute__((address_space(3))) unsigned int*)(unsigned int)(unsigned long long)l,
      16, 0, 0);
}

#define VWAIT(N) asm volatile("s_waitcnt vmcnt(" #N ")" ::: "memory")

// ---------------------------------------------------------------- prep kernels

__global__ void relw_kernel(const float* __restrict__ rel_embs,
                            const float* __restrict__ w_rel,
                            const float* __restrict__ b_rel,
                            float* __restrict__ rel_w) {
  const int tr = blockIdx.x;            // t*8 + r, 128 total
  const float* row = rel_embs + (size_t)tr * 1024;
  const int lane = threadIdx.x;         // 64 threads
  float s = 0.f;
  for (int i = lane; i < 1024; i += 64) s += row[i] * w_rel[i];
  for (int off = 32; off > 0; off >>= 1) s += __shfl_down(s, off, 64);
  if (lane == 0) rel_w[tr] = 1.f / (1.f + __expf(-(s + b_rel[0])));
}

__global__ void cvt_f32_bf16(const float* __restrict__ in, u16* __restrict__ out, int n4) {
  int i = blockIdx.x * blockDim.x + threadIdx.x;
  if (i >= n4) return;
  float4 v = ((const float4*)in)[i];
  ushort4 o;
  o.x = f2bf(v.x); o.y = f2bf(v.y); o.z = f2bf(v.z); o.w = f2bf(v.w);
  ((ushort4*)out)[i] = o;
}

// all four 1024x1024 weight matrices in one launch: 4*262144 float4's
__global__ void cvt_w4(const float* __restrict__ Wq, const float* __restrict__ Wk,
                       const float* __restrict__ Wv, const float* __restrict__ Wo,
                       u16* __restrict__ Wcat, u16* __restrict__ Wob) {
  const int i = blockIdx.x * 256 + threadIdx.x;     // 0 .. 1048575
  const int w = i >> 18;                            // 262144 float4 per matrix
  const int j = i & 0x3ffff;
  const float* src = (w == 0) ? Wq : (w == 1) ? Wk : (w == 2) ? Wv : Wo;
  u16* dst = (w == 3) ? Wob : (Wcat + ((size_t)w << 20));
  float4 v = ((const float4*)src)[j];
  ushort4 o;
  o.x = f2bf(v.x); o.y = f2bf(v.y); o.z = f2bf(v.z); o.w = f2bf(v.w);
  ((ushort4*)dst)[j] = o;
}

// ---------------------------------------------------------------- 256^2 mainloop
// A [M,1024] row-major bf16, B [N,1024] row-major bf16 (out = x@W.T), K=1024.
// Block tile 256x256, BK=64, 512 threads = 8 waves (2M x 4N), wave 128x64 out.
// LDS 128KiB: buf0{A,B} buf1{A,B}, each region 256 rows x 64 bf16 (128B/row).
// Swizzle: 16B chunk c of row r lives at physical chunk c ^ (r&7).
// Pipeline: per tile t issue next-tile stages ph0:B0-3 ph1:A_r0,r2 ph2:A_r1,r3;
// counted waits vmcnt(6) @ ph1->2 (A_r1,r3 of t land), vmcnt(2) @ tile end
// (B+A_r0,r2 of t+1 land; A_r1,r3 of t+1 stay in flight).
// NO explicit lgkm drain: compiler emits counted lgkmcnt per MFMA operand.

__device__ __forceinline__ void mainloop256(const u16* __restrict__ A,
                                            const u16* __restrict__ B,
                                            u16* lds, int m0, int n0,
                                            f32x4 (&acc)[8][4]) {
  const int tid  = threadIdx.x;          // 512
  const int lane = tid & 63;
  const int w    = tid >> 6;             // 8 waves
  const int wm   = w >> 2, wn = w & 3;
  const int fr   = lane & 15, fq = lane >> 4;
  const int swz  = fr & 7;

  const unsigned A0 = 0, B0 = 16384, A1 = 32768, B1 = 49152;  // u16 offsets

  // staging descriptors: row&7 and pc are r-invariant (r step = 64 rows)
  const int srow = tid >> 3;                       // row for slot r=0
  const int lc   = (tid & 7) ^ (srow & 7);         // logical chunk stored here
  const u16* a0p = A + (size_t)(m0 + srow) * 1024 + lc * 8;
  const u16* b0p = B + (size_t)(n0 + srow) * 1024 + lc * 8;
  const unsigned d0 = (unsigned)((tid & ~63) * 8); // wave-uniform dest (u16)

  // fragment read bases per (buffer, ksub); i becomes imm offset (i*2048B)
  const u16 *ap0[2], *ap1[2], *bp0[2], *bp1[2];
#pragma unroll
  for (int ks = 0; ks < 2; ++ks) {
    const unsigned ck = (unsigned)((((ks << 2) + fq) ^ swz) << 3);
    ap0[ks] = lds + A0 + (wm * 128 + fr) * 64 + ck;
    ap1[ks] = lds + A1 + (wm * 128 + fr) * 64 + ck;
    bp0[ks] = lds + B0 + (wn * 64 + fr) * 64 + ck;
    bp1[ks] = lds + B1 + (wn * 64 + fr) * 64 + ck;
  }

#define STAGE_B4(BO)                                                           \
  do {                                                                         \
    gld_lds16(b0p + 0 * 65536, lds + (BO) + d0 + 0 * 4096);                    \
    gld_lds16(b0p + 1 * 65536, lds + (BO) + d0 + 1 * 4096);                    \
    gld_lds16(b0p + 2 * 65536, lds + (BO) + d0 + 2 * 4096);                    \
    gld_lds16(b0p + 3 * 65536, lds + (BO) + d0 + 3 * 4096);                    \
    b0p += 64;                                                                 \
  } while (0)

#define STAGE_A2(ra, rb, AO)                                                   \
  do {                                                                         \
    gld_lds16(a0p + (ra) * 65536, lds + (AO) + d0 + (ra) * 4096);              \
    gld_lds16(a0p + (rb) * 65536, lds + (AO) + d0 + (rb) * 4096);              \
  } while (0)

#define PHASE_Q(q, ap, STMT)                                                   \
  do {                                                                         \
    short8 a0k0 = *(const short8*)((ap)[0] + (2*(q))   * 1024);                \
    short8 a1k0 = *(const short8*)((ap)[0] + (2*(q)+1) * 1024);                \
    short8 a0k1 = *(const short8*)((ap)[1] + (2*(q))   * 1024);                \
    short8 a1k1 = *(const short8*)((ap)[1] + (2*(q)+1) * 1024);                \
    STMT;                                                                      \
    __builtin_amdgcn_s_barrier();                                              \
    __builtin_amdgcn_s_setprio(1);                                             \
    _Pragma("unroll")                                                          \
    for (int j = 0; j < 4; ++j) {                                              \
      acc[2*(q)][j]   = __builtin_amdgcn_mfma_f32_16x16x32_bf16(a0k0, bgv[j][0], acc[2*(q)][j],   0, 0, 0); \
      acc[2*(q)+1][j] = __builtin_amdgcn_mfma_f32_16x16x32_bf16(a1k0, bgv[j][0], acc[2*(q)+1][j], 0, 0, 0); \
    }                                                                          \
    _Pragma("unroll")                                                          \
    for (int j = 0; j < 4; ++j) {                                              \
      acc[2*(q)][j]   = __builtin_amdgcn_mfma_f32_16x16x32_bf16(a0k1, bgv[j][1], acc[2*(q)][j],   0, 0, 0); \
      acc[2*(q)+1][j] = __builtin_amdgcn_mfma_f32_16x16x32_bf16(a1k1, bgv[j][1], acc[2*(q)+1][j], 0, 0, 0); \
    }                                                                          \
    __builtin_amdgcn_s_setprio(0);                                             \
  } while (0)

#define BGV_LOAD(bp)                                                           \
  _Pragma("unroll")                                                            \
  for (int j = 0; j < 4; ++j) {                                                \
    bgv[j][0] = *(const short8*)((bp)[0] + j * 1024);                          \
    bgv[j][1] = *(const short8*)((bp)[1] + j * 1024);                          \
  }

// steady-state K-tile: stages next tile into (AO_N,BO_N); counted waits only
#define KTILE(ap, bp, AO_N, BO_N)                                              \
  do {                                                                         \
    short8 bgv[4][2];                                                          \
    BGV_LOAD(bp);                                                              \
    PHASE_Q(0, ap, { STAGE_B4(BO_N); });                                       \
    __builtin_amdgcn_s_barrier();                                              \
    PHASE_Q(1, ap, { STAGE_A2(0, 2, AO_N); });                                 \
    VWAIT(6);                                                                  \
    __builtin_amdgcn_s_barrier();                                              \
    PHASE_Q(2, ap, { STAGE_A2(1, 3, AO_N); a0p += 64; });                      \
    __builtin_amdgcn_s_barrier();                                              \
    PHASE_Q(3, ap, {});                                                       \
    VWAIT(2);                                                                  \
    __builtin_amdgcn_s_barrier();                                              \
  } while (0)

// last K-tile: no staging; drain the 2 leftover A loads at ph1->2
#define KTILE_LAST(ap, bp)                                                     \
  do {                                                                         \
    short8 bgv[4][2];                                                          \
    BGV_LOAD(bp);                                                              \
    PHASE_Q(0, ap, {});                                                       \
    __builtin_amdgcn_s_barrier();                                              \
    PHASE_Q(1, ap, {});                                                       \
    VWAIT(0);                                                                  \
    __builtin_amdgcn_s_barrier();                                              \
    PHASE_Q(2, ap, {});                                                       \
    __builtin_amdgcn_s_barrier();                                              \
    PHASE_Q(3, ap, {});                                                       \
    __builtin_amdgcn_s_barrier();                                              \
  } while (0)

  // prologue: stage tile 0 -> buf0 in pipeline order B0-3, A_r0, A_r2, A_r1, A_r3
  gld_lds16(b0p + 0 * 65536, lds + B0 + d0 + 0 * 4096);
  gld_lds16(b0p + 1 * 65536, lds + B0 + d0 + 1 * 4096);
  gld_lds16(b0p + 2 * 65536, lds + B0 + d0 + 2 * 4096);
  gld_lds16(b0p + 3 * 65536, lds + B0 + d0 + 3 * 4096);
  gld_lds16(a0p + 0 * 65536, lds + A0 + d0 + 0 * 4096);
  gld_lds16(a0p + 2 * 65536, lds + A0 + d0 + 2 * 4096);
  gld_lds16(a0p + 1 * 65536, lds + A0 + d0 + 1 * 4096);
  gld_lds16(a0p + 3 * 65536, lds + A0 + d0 + 3 * 4096);
  a0p += 64; b0p += 64;
  VWAIT(2);                       // B(0)+A_r0,r2 landed; A_r1,r3 in flight
  __builtin_amdgcn_s_barrier();

  for (int it = 0; it < 7; ++it) {       // tiles 0..13
    KTILE(ap0, bp0, A1, B1);
    KTILE(ap1, bp1, A0, B0);
  }
  KTILE(ap0, bp0, A1, B1);               // tile 14 (stages tile 15)
  KTILE_LAST(ap1, bp1);                  // tile 15

#undef STAGE_B4
#undef STAGE_A2
#undef PHASE_Q
#undef BGV_LOAD
#undef KTILE
#undef KTILE_LAST
}

// bijective XCD swizzle for nwg % 8 == 0
__device__ __forceinline__ void xcd_swizzle(int nx, int ny, int& bx, int& by) {
  const int nwg = nx * ny;
  int bid = by * nx + bx;
  bid = (bid & 7) * (nwg >> 3) + (bid >> 3);
  bx = bid % nx;
  by = bid / nx;
}

// GEMM1: X[16384,1024] @ Wcat[3072,1024].T -> Q/K/V stored TRANSPOSED [t][d][b]
__global__ __launch_bounds__(512, 1)
void gemm_qkv(const u16* __restrict__ A, const u16* __restrict__ Bw,
              const float* __restrict__ bq,
              u16* __restrict__ Qt, u16* __restrict__ Kt, u16* __restrict__ Vt) {
  __shared__ __align__(16) u16 lds[65536];   // 128 KiB
  int bx = blockIdx.x, by = blockIdx.y;
  xcd_swizzle(gridDim.x, gridDim.y, bx, by);
  const int n0 = bx * 256;                   // d within QKV-cat (256|1024 ok)
  const int m0 = by * 256;                   // t*1024 + b (256|1024 ok)
  f32x4 acc[8][4];
#pragma unroll
  for (int i = 0; i < 8; ++i)
#pragma unroll
    for (int j = 0; j < 4; ++j) acc[i][j] = (f32x4){0.f, 0.f, 0.f, 0.f};

  mainloop256(A, Bw, lds, m0, n0, acc);
  __syncthreads();   // real fence: all LDS reads retired before scatter reuse

  const int tid  = threadIdx.x;
  const int lane = tid & 63;
  const int w    = tid >> 6;
  const int wm   = w >> 2, wn = w & 3;
  const int colw = lane & 15, roww = (lane >> 4) * 4;
  const int t = m0 >> 10, b0 = m0 & 1023;
  const int sel = n0 >> 10, dbase = n0 & 1023;
  u16* outp = (sel == 0) ? Qt : (sel == 1) ? Kt : Vt;

  // scatter BOTH wm-halves concurrently: region[wm] = 64KiB at wm*32768 u16.
  // phys byte in region = d*256 + (Lbyte ^ ((d&7)<<4)); paired 8B stores.
  {
    char* reg = (char*)(lds + wm * 32768);
#pragma unroll
    for (int j = 0; j < 4; ++j) {
      const int dl = wn * 64 + j * 16 + colw;
      const float badd = (sel == 0) ? bq[dbase + dl] : 0.f;
      char* rowp = reg + (unsigned)dl * 256;
      const unsigned sx = ((unsigned)dl & 7) << 4;
#pragma unroll
      for (int i = 0; i < 8; ++i) {
        const int bl = i * 16 + roww;           // multiple of 4
        uint2 pv;
        pv.x = (unsigned)f2bf(acc[i][j][0] + badd)
             | ((unsigned)f2bf(acc[i][j][1] + badd) << 16);
        pv.y = (unsigned)f2bf(acc[i][j][2] + badd)
             | ((unsigned)f2bf(acc[i][j][3] + badd) << 16);
        *(uint2*)(rowp + (((unsigned)bl * 2) ^ sx)) = pv;
      }
    }
  }
  __syncthreads();
  // writeout: 2 regions x 4096 uint4, coalesced rows into [t][d][b]
#pragma unroll
  for (int pass = 0; pass < 2; ++pass) {
    const char* regp = (const char*)(lds + pass * 32768);
#pragma unroll
    for (int rr = 0; rr < 8; ++rr) {
      const int slot = rr * 512 + tid;          // 4096 slots = 256 rows x 16
      const int row = slot >> 4, c16 = slot & 15;
      const uint4 v = *(const uint4*)(regp + (unsigned)row * 256
                                      + (((unsigned)c16 * 16) ^ (((unsigned)row & 7) << 4)));
      *(uint4*)(outp + ((size_t)t << 20) + (size_t)(dbase + row) * 1024
                + b0 + pass * 128 + c16 * 8) = v;
    }
  }
}

// GEMM2: ctx[16384,1024] @ Wo[1024,1024].T + bo -> fp32 out
__global__ __launch_bounds__(512, 1)
void gemm_out(const u16* __restrict__ A, const u16* __restrict__ Bw,
              const float* __restrict__ bo, float* __restrict__ out) {
  __shared__ __align__(16) u16 lds[65536];
  int bx = blockIdx.x, by = blockIdx.y;
  xcd_swizzle(gridDim.x, gridDim.y, bx, by);
  const int n0 = bx * 256;
  const int m0 = by * 256;
  f32x4 acc[8][4];
#pragma unroll
  for (int i = 0; i < 8; ++i)
#pragma unroll
    for (int j = 0; j < 4; ++j) acc[i][j] = (f32x4){0.f, 0.f, 0.f, 0.f};

  mainloop256(A, Bw, lds, m0, n0, acc);
  // epilogue touches no LDS -> no extra fence needed

  const int lane = threadIdx.x & 63;
  const int w    = threadIdx.x >> 6;
  const int wm   = w >> 2, wn = w & 3;
  const int colw = lane & 15, roww = (lane >> 4) * 4;
#pragma unroll
  for (int j = 0; j < 4; ++j) {
    const int gn = n0 + wn * 64 + j * 16 + colw;
    const float bov = bo[gn];
#pragma unroll
    for (int i = 0; i < 8; ++i) {
      const int gm = m0 + wm * 128 + i * 16 + roww;
#pragma unroll
      for (int r = 0; r < 4; ++r)
        out[(size_t)(gm + r) * 1024 + gn] = acc[i][j][r] + bov;
    }
  }
}

// ---------------------------------------------------------------- attention
// attn5: ONE b per thread (262144 threads = 4096 waves = 16 waves/CU).
// Streams d; loads are 2B/lane (128B/wave contiguous). acc[8] in regs.
// Output staged per 32-d half via LDS (pad 34 -> 2-way banks), coalesced rows.
__global__ __launch_bounds__(256)
void attn5(const u16* __restrict__ Qt, const u16* __restrict__ Kt,
           const u16* __restrict__ Vt,
           const float* __restrict__ relw, const int* __restrict__ rel_idx,
           const float* __restrict__ bk, const float* __restrict__ bv,
           u16* __restrict__ ctx) {
  const int tid = threadIdx.x;
  const int h = blockIdx.y, t = blockIdx.z;
  const int b0 = blockIdx.x * 256;          // block covers b0 .. b0+255
  const int b = b0 + tid;
  const int hd = h * 64;

  __shared__ u16  st[256 * 34];             // [256 b][32 d + 2 pad]  17.0KB
  __shared__ float bks[64], bvs[64], rws[8];
  __shared__ int   rids[8];

  if (tid < 64) { bks[tid] = bk[hd + tid]; bvs[tid] = bv[hd + tid]; }
  else if (tid < 72) { rws[tid - 64] = relw[t * 8 + (tid - 64)];
                       rids[tid - 64] = rel_idx[t * 8 + (tid - 64)]; }
  __syncthreads();

  // element offsets at d=0 into [t][1024 d][1024 b] arrays
  const unsigned qoff = ((unsigned)t << 20) + ((unsigned)hd << 10) + (unsigned)b;
  unsigned koff[8];
#pragma unroll
  for (int r = 0; r < 8; ++r)
    koff[r] = ((unsigned)rids[r] << 20) + ((unsigned)hd << 10) + (unsigned)b;

  // ---- scores
  float acc[8];
#pragma unroll
  for (int r = 0; r < 8; ++r) acc[r] = 0.f;
  float qbk = 0.f;
#pragma unroll 4
  for (int d = 0; d < 64; ++d) {
    const float q = bf2f(Qt[qoff + d * 1024]);
    qbk += q * bks[d];
#pragma unroll
    for (int r = 0; r < 8; ++r)
      acc[r] += q * bf2f(Kt[koff[r] + d * 1024]);
  }

  // ---- softmax -> w[r] = attn_r * rw_r
  float w[8];
  {
    float s[8], mx = -1e30f;
#pragma unroll
    for (int r = 0; r < 8; ++r) {
      s[r] = (rws[r] * acc[r] + qbk) * 0.125f;
      mx = fmaxf(mx, s[r]);
    }
    float sum = 0.f;
#pragma unroll
    for (int r = 0; r < 8; ++r) { s[r] = __expf(s[r] - mx); sum += s[r]; }
    const float inv = 1.f / sum;
#pragma unroll
    for (int r = 0; r < 8; ++r) w[r] = s[r] * inv * rws[r];
  }

  // ---- context: two 32-d halves; stage [b][d] in LDS, coalesced writeout
  for (int half = 0; half < 2; ++half) {
#pragma unroll
    for (int dp = 0; dp < 32; dp += 2) {
      const int d = half * 32 + dp;
      float o0 = bvs[d];
      float o1 = bvs[d + 1];
#pragma unroll
      for (int r = 0; r < 8; ++r) {
        o0 += w[r] * bf2f(Vt[koff[r] + d * 1024]);
        o1 += w[r] * bf2f(Vt[koff[r] + (d + 1) * 1024]);
      }
      const unsigned p = (unsigned)f2bf(o0) | ((unsigned)f2bf(o1) << 16);
      *(unsigned*)(st + tid * 34 + dp) = p;   // byte 68*tid+2dp, 4B-aligned
    }
    __syncthreads();
    // writeout: 256 rows x 64B (32 d); 8 lanes x 8B per row, 8 passes
    {
      const int sub = tid & 7;
      const int rbase = tid >> 3;              // 0..31
#pragma unroll
      for (int p = 0; p < 8; ++p) {
        const int row = p * 32 + rbase;
        const uint2 v = *(const uint2*)(st + row * 34 + sub * 4);
        *(uint2*)(ctx + ((size_t)(t * 1024 + b0 + row)) * 1024
                  + hd + half * 32 + sub * 4) = v;
      }
    }
    __syncthreads();   // st reused by next half
  }
}

// ---------------------------------------------------------------- launch

extern "C" void kernel_launch(void* const* d_in, const int* in_sizes, int n_in,
                              void* d_out, int out_size, void* d_ws, size_t ws_size,
                              hipStream_t stream) {
  const float* table = (const float*)d_in[0];
  const float* rele  = (const float*)d_in[1];
  const int*   ridx  = (const int*)d_in[2];
  const float* Wq    = (const float*)d_in[3];
  const float* bq    = (const float*)d_in[4];
  const float* Wk    = (const float*)d_in[5];
  const float* bk    = (const float*)d_in[6];
  const float* Wv    = (const float*)d_in[7];
  const float* bv    = (const float*)d_in[8];
  const float* Wo    = (const float*)d_in[9];
  const float* bo    = (const float*)d_in[10];
  const float* wr    = (const float*)d_in[11];
  const float* br    = (const float*)d_in[12];
  float* out = (float*)d_out;

  char* ws = (char*)d_ws;
  const size_t MB = 1024 * 1024;
  u16*  Xbf  = (u16*)(ws);                    // 32 MB  [16384,1024] bf16 (also ctx)
  u16*  Kt   = (u16*)(ws + 32  * MB);         // 32 MB  [16][1024 d][1024 b]
  u16*  Vt   = (u16*)(ws + 64  * MB);         // 32 MB
  u16*  Qt   = (u16*)(ws + 96  * MB);         // 32 MB
  u16*  Wcat = (u16*)(ws + 128 * MB);         // 6 MB   [3072,1024] (Wq|Wk|Wv)
  u16*  Wob  = (u16*)(ws + 134 * MB);         // 2 MB
  float* relw = (float*)(ws + 136 * MB);      // 512 B
  u16*  ctxb = Xbf;                           // reuse: Xbf dead after gemm_qkv

  relw_kernel<<<128, 64, 0, stream>>>(rele, wr, br, relw);
  cvt_f32_bf16<<<16384, 256, 0, stream>>>(table, Xbf, 4194304);
  cvt_w4<<<4096, 256, 0, stream>>>(Wq, Wk, Wv, Wo, Wcat, Wob);

  gemm_qkv<<<dim3(12, 64), 512, 0, stream>>>(Xbf, Wcat, bq, Qt, Kt, Vt);
  attn5<<<dim3(4, 16, 16), 256, 0, stream>>>(Qt, Kt, Vt, relw, ridx, bk, bv, ctxb);
  gemm_out<<<dim3(4, 64), 512, 0, stream>>>(ctxb, Wob, bo, out);
}